// Round 3
// baseline (162.050 us; speedup 1.0000x reference)
//
#include <hip/hip_runtime.h>
#include <hip/hip_bf16.h>

// Problem dims (fixed by reference)
constexpr int Bb = 8;
constexpr int Dd = 64;
constexpr int Tt = 8192;
constexpr int Kk = 1024;
constexpr int BT = Bb * Tt;            // 65536 rows
constexpr int NTOT = Bb * Dd * Tt;     // 4194304 elements

// Output layout (float32): [codes BT][quantized NTOT][loss 1]
constexpr int OUT_Q_OFF = BT;
constexpr int OUT_LOSS_OFF = BT + NTOT;

// Workspace layout (bytes)
constexpr size_t WS_CODES_OFF = 0;                      // int32[BT]
constexpr size_t WS_PREC_OFF  = (size_t)BT * 4;         // float[K]
constexpr size_t WS_PART_OFF  = WS_PREC_OFF + Kk * 4;   // float[256]

// ---------------- Kernel P: prec[k] = ||e_k||^2 ----------------
__global__ void __launch_bounds__(256) prec_kernel(const float* __restrict__ cb,
                                                   float* __restrict__ prec) {
    int k = blockIdx.x * 256 + threadIdx.x;
    if (k < Kk) {
        const float4* row = reinterpret_cast<const float4*>(cb + (size_t)k * Dd);
        float s = 0.f;
#pragma unroll
        for (int i = 0; i < 16; ++i) {
            float4 v = row[i];
            s = fmaf(v.x, v.x, s); s = fmaf(v.y, v.y, s);
            s = fmaf(v.z, v.z, s); s = fmaf(v.w, v.w, s);
        }
        prec[k] = s;
    }
}

// ---------------- Kernel A: argmin over K ----------------
// 64 rows per block (one per lane), 4 waves split K within staged chunks.
// Score replicates the reference's fp32 evaluation ORDER so that its
// magnitude-64 quantization (ulp ~7.6e-6) and resulting argmin ties match:
//   t1  = fp32( zsq + esq[k] )        // numpy's (A + B), rounded once
//   s_k = fp32( t1 - 2*dot_k )        // numpy's  ... - 2.0*C, rounded once -> fmaf
// Ties (equal fp32 scores) resolve to the LOWEST k, matching np.argmin.
constexpr int ROWS_PB = 64;
constexpr int SPLITS = 4;     // waves per block
constexpr int CHUNK = 128;    // codebook rows staged per iteration
constexpr int KPW = CHUNK / SPLITS;  // 32 k's per wave per chunk

__global__ void __launch_bounds__(256) argmin_kernel(
    const float* __restrict__ z, const float* __restrict__ cb,
    const float* __restrict__ prec, float* __restrict__ out,
    int* __restrict__ codes_i)
{
    __shared__ float lds_e[CHUNK * Dd];   // 32 KiB
    __shared__ float lds_p[CHUNK];
    __shared__ float s_best[SPLITS][ROWS_PB];
    __shared__ int   s_bidx[SPLITS][ROWS_PB];

    const int tid = threadIdx.x;
    const int rl = tid & 63;      // lane = row within block
    const int sp = tid >> 6;      // wave = K-split
    const int row = blockIdx.x * ROWS_PB + rl;
    const int b = row >> 13;      // T = 8192
    const int t = row & (Tt - 1);
    const float* zrow = z + (size_t)b * (Dd * Tt) + t;

    // z row into registers (coalesced across lanes for each d)
    float zr[Dd];
#pragma unroll
    for (int d = 0; d < Dd; ++d) zr[d] = zrow[(size_t)d * Tt];

    // ||z||^2 in fp32. Exact numpy bit-match NOT required: any fp32 result in
    // the same binade differs from numpy's by an exact grid multiple, which
    // shifts all d[k] equally through the rounding -> argmin/ties preserved.
    float zsq = 0.f;
#pragma unroll
    for (int d = 0; d < Dd; ++d) zsq = fmaf(zr[d], zr[d], zsq);

    float best = 3.4e38f;
    int bidx = 0;

    for (int c = 0; c < Kk; c += CHUNK) {
        __syncthreads();
        // stage CHUNK*64 floats, coalesced
        const float4* src = reinterpret_cast<const float4*>(cb + (size_t)c * Dd);
        float4* dst = reinterpret_cast<float4*>(lds_e);
#pragma unroll
        for (int i = 0; i < (CHUNK * Dd / 4) / 256; ++i)   // 8 iters
            dst[tid + i * 256] = src[tid + i * 256];
        if (tid < CHUNK) lds_p[tid] = prec[c + tid];
        __syncthreads();

        // this wave's k range within the chunk, ascending
        const int k0base = sp * KPW;
        for (int kk = k0base; kk < k0base + KPW; kk += 4) {
            const float4* e0 = reinterpret_cast<const float4*>(lds_e + (kk + 0) * Dd);
            const float4* e1 = reinterpret_cast<const float4*>(lds_e + (kk + 1) * Dd);
            const float4* e2 = reinterpret_cast<const float4*>(lds_e + (kk + 2) * Dd);
            const float4* e3 = reinterpret_cast<const float4*>(lds_e + (kk + 3) * Dd);
            float a0 = 0.f, a1 = 0.f, a2 = 0.f, a3 = 0.f;
#pragma unroll
            for (int d4 = 0; d4 < 16; ++d4) {
                float4 va = e0[d4], vb = e1[d4], vc = e2[d4], vd = e3[d4];
                const float z0 = zr[4 * d4 + 0], z1 = zr[4 * d4 + 1];
                const float z2 = zr[4 * d4 + 2], z3 = zr[4 * d4 + 3];
                a0 = fmaf(va.x, z0, a0); a0 = fmaf(va.y, z1, a0);
                a0 = fmaf(va.z, z2, a0); a0 = fmaf(va.w, z3, a0);
                a1 = fmaf(vb.x, z0, a1); a1 = fmaf(vb.y, z1, a1);
                a1 = fmaf(vb.z, z2, a1); a1 = fmaf(vb.w, z3, a1);
                a2 = fmaf(vc.x, z0, a2); a2 = fmaf(vc.y, z1, a2);
                a2 = fmaf(vc.z, z2, a2); a2 = fmaf(vc.w, z3, a2);
                a3 = fmaf(vd.x, z0, a3); a3 = fmaf(vd.y, z1, a3);
                a3 = fmaf(vd.z, z2, a3); a3 = fmaf(vd.w, z3, a3);
            }
            // Reference-order fp32: t1 = round(zsq + esq), s = round(t1 - 2*dot)
            const float t10 = zsq + lds_p[kk + 0];
            const float t11 = zsq + lds_p[kk + 1];
            const float t12 = zsq + lds_p[kk + 2];
            const float t13 = zsq + lds_p[kk + 3];
            const float s0 = fmaf(-2.f, a0, t10);
            const float s1 = fmaf(-2.f, a1, t11);
            const float s2 = fmaf(-2.f, a2, t12);
            const float s3 = fmaf(-2.f, a3, t13);
            const int kg = c + kk;
            if (s0 < best) { best = s0; bidx = kg + 0; }
            if (s1 < best) { best = s1; bidx = kg + 1; }
            if (s2 < best) { best = s2; bidx = kg + 2; }
            if (s3 < best) { best = s3; bidx = kg + 3; }
        }
    }

    s_best[sp][rl] = best;
    s_bidx[sp][rl] = bidx;
    __syncthreads();
    if (sp == 0) {
#pragma unroll
        for (int s = 1; s < SPLITS; ++s) {
            const float ob = s_best[s][rl];
            const int oi = s_bidx[s][rl];
            if (ob < best || (ob == best && oi < bidx)) { best = ob; bidx = oi; }
        }
        codes_i[row] = bidx;
        out[row] = (float)bidx;
    }
}

// ---------------- Kernel B: quantized + loss partials ----------------
__global__ void __launch_bounds__(256) quant_kernel(
    const float* __restrict__ z, const float* __restrict__ cb,
    const int* __restrict__ codes_i, float* __restrict__ out,
    float* __restrict__ partials)
{
    const int row = blockIdx.x * 256 + threadIdx.x;  // grid = 256 blocks
    const int b = row >> 13;
    const int t = row & (Tt - 1);
    const int code = codes_i[row];
    const float4* crow = reinterpret_cast<const float4*>(cb + (size_t)code * Dd);
    const float* zbase = z + (size_t)b * (Dd * Tt) + t;
    float* obase = out + OUT_Q_OFF + (size_t)b * (Dd * Tt) + t;

    float acc = 0.f;
#pragma unroll
    for (int d4 = 0; d4 < 16; ++d4) {
        float4 v = crow[d4];
        float vv[4] = {v.x, v.y, v.z, v.w};
#pragma unroll
        for (int j = 0; j < 4; ++j) {
            const int d = d4 * 4 + j;
            const float zv = zbase[(size_t)d * Tt];
            const float diff = vv[j] - zv;
            acc = fmaf(diff, diff, acc);
            obase[(size_t)d * Tt] = vv[j];
        }
    }

    __shared__ float red[256];
    red[threadIdx.x] = acc;
    __syncthreads();
#pragma unroll
    for (int s = 128; s > 0; s >>= 1) {
        if (threadIdx.x < s) red[threadIdx.x] += red[threadIdx.x + s];
        __syncthreads();
    }
    if (threadIdx.x == 0) partials[blockIdx.x] = red[0];
}

// ---------------- Kernel C: final loss reduce ----------------
__global__ void __launch_bounds__(256) loss_kernel(const float* __restrict__ partials,
                                                   float* __restrict__ out) {
    __shared__ float red[256];
    red[threadIdx.x] = partials[threadIdx.x];  // exactly 256 partials
    __syncthreads();
#pragma unroll
    for (int s = 128; s > 0; s >>= 1) {
        if (threadIdx.x < s) red[threadIdx.x] += red[threadIdx.x + s];
        __syncthreads();
    }
    if (threadIdx.x == 0)
        out[OUT_LOSS_OFF] = red[0] * (1.0f / (float)NTOT);
}

extern "C" void kernel_launch(void* const* d_in, const int* in_sizes, int n_in,
                              void* d_out, int out_size, void* d_ws, size_t ws_size,
                              hipStream_t stream) {
    const float* z = (const float*)d_in[0];
    const float* cb = (const float*)d_in[1];
    float* out = (float*)d_out;

    char* ws = (char*)d_ws;
    int* codes_i = (int*)(ws + WS_CODES_OFF);
    float* prec = (float*)(ws + WS_PREC_OFF);
    float* partials = (float*)(ws + WS_PART_OFF);

    prec_kernel<<<(Kk + 255) / 256, 256, 0, stream>>>(cb, prec);
    argmin_kernel<<<BT / ROWS_PB, 256, 0, stream>>>(z, cb, prec, out, codes_i);
    quant_kernel<<<BT / 256, 256, 0, stream>>>(z, cb, codes_i, out, partials);
    loss_kernel<<<1, 256, 0, stream>>>(partials, out);
}

// Round 4
// 153.608 us; speedup vs baseline: 1.0550x; 1.0550x over previous
//
#include <hip/hip_runtime.h>
#include <hip/hip_bf16.h>

// Problem dims (fixed by reference)
constexpr int Bb = 8;
constexpr int Dd = 64;
constexpr int Tt = 8192;
constexpr int Kk = 1024;
constexpr int BT = Bb * Tt;            // 65536 rows
constexpr int NTOT = Bb * Dd * Tt;     // 4194304 elements

// Output layout (float32): [codes BT][quantized NTOT][loss 1]
constexpr int OUT_Q_OFF = BT;
constexpr int OUT_LOSS_OFF = BT + NTOT;

// Workspace layout (bytes)
constexpr size_t WS_CODES_OFF = 0;                      // int32[BT]
constexpr size_t WS_PREC_OFF  = (size_t)BT * 4;         // float[K]
constexpr size_t WS_PART_OFF  = WS_PREC_OFF + Kk * 4;   // float[256]

// ---------------- Kernel P: prec[k] = ||e_k||^2 ----------------
__global__ void __launch_bounds__(256) prec_kernel(const float* __restrict__ cb,
                                                   float* __restrict__ prec) {
    int k = blockIdx.x * 256 + threadIdx.x;
    if (k < Kk) {
        const float4* row = reinterpret_cast<const float4*>(cb + (size_t)k * Dd);
        float s = 0.f;
#pragma unroll
        for (int i = 0; i < 16; ++i) {
            float4 v = row[i];
            s = fmaf(v.x, v.x, s); s = fmaf(v.y, v.y, s);
            s = fmaf(v.z, v.z, s); s = fmaf(v.w, v.w, s);
        }
        prec[k] = s;
    }
}

// ---------------- Kernel A: argmin over K ----------------
// 64 rows per block (one per lane), 4 waves split K within staged chunks.
// Score replicates the reference's fp32 evaluation ORDER so that its
// magnitude-64 quantization (ulp ~7.6e-6) and resulting argmin ties match:
//   t1  = fp32( zsq + esq[k] )        // numpy's (A + B), rounded once
//   s_k = fp32( t1 - 2*dot_k )        // numpy's  ... - 2.0*C, one more rounding -> fmaf
// Ties (equal fp32 scores) resolve to the LOWEST k, matching np.argmin.
//
// __launch_bounds__(256, 4): LDS (35 KB) caps us at 4 blocks/CU = 4 waves/SIMD
// anyway; ask the compiler for the matching 128-VGPR budget so the 64-float
// z-row stays register-resident. (Round-3 evidence: bare launch_bounds gave
// VGPR_Count=64 — an 8-wave budget — forcing z re-loads inside the k-loop and
// 2.2x VALU inflation.)
constexpr int ROWS_PB = 64;
constexpr int SPLITS = 4;     // waves per block
constexpr int CHUNK = 128;    // codebook rows staged per iteration
constexpr int KPW = CHUNK / SPLITS;  // 32 k's per wave per chunk

__global__ void __launch_bounds__(256, 4) argmin_kernel(
    const float* __restrict__ z, const float* __restrict__ cb,
    const float* __restrict__ prec, float* __restrict__ out,
    int* __restrict__ codes_i)
{
    __shared__ float lds_e[CHUNK * Dd];   // 32 KiB
    __shared__ float lds_p[CHUNK];
    __shared__ float s_best[SPLITS][ROWS_PB];
    __shared__ int   s_bidx[SPLITS][ROWS_PB];

    const int tid = threadIdx.x;
    const int rl = tid & 63;      // lane = row within block
    const int sp = tid >> 6;      // wave = K-split
    const int row = blockIdx.x * ROWS_PB + rl;
    const int b = row >> 13;      // T = 8192
    const int t = row & (Tt - 1);
    const float* zrow = z + (size_t)b * (Dd * Tt) + t;

    // z row into registers (coalesced across lanes for each d)
    float zr[Dd];
#pragma unroll
    for (int d = 0; d < Dd; ++d) zr[d] = zrow[(size_t)d * Tt];

    // ||z||^2 in fp32. Exact numpy bit-match NOT required: any fp32 result in
    // the same binade differs from numpy's by an exact grid multiple, which
    // shifts all d[k] equally through the rounding -> argmin/ties preserved.
    float zsq = 0.f;
#pragma unroll
    for (int d = 0; d < Dd; ++d) zsq = fmaf(zr[d], zr[d], zsq);

    float best = 3.4e38f;
    int bidx = 0;

    for (int c = 0; c < Kk; c += CHUNK) {
        __syncthreads();
        // stage CHUNK*64 floats, coalesced
        const float4* src = reinterpret_cast<const float4*>(cb + (size_t)c * Dd);
        float4* dst = reinterpret_cast<float4*>(lds_e);
#pragma unroll
        for (int i = 0; i < (CHUNK * Dd / 4) / 256; ++i)   // 8 iters
            dst[tid + i * 256] = src[tid + i * 256];
        if (tid < CHUNK) lds_p[tid] = prec[c + tid];
        __syncthreads();

        // this wave's k range within the chunk, ascending
        const int k0base = sp * KPW;
#pragma unroll 2
        for (int kk = k0base; kk < k0base + KPW; kk += 4) {
            float a0 = 0.f, a1 = 0.f, a2 = 0.f, a3 = 0.f;
            {
                const float4* e0 = reinterpret_cast<const float4*>(lds_e + (kk + 0) * Dd);
                const float4* e1 = reinterpret_cast<const float4*>(lds_e + (kk + 1) * Dd);
#pragma unroll
                for (int d4 = 0; d4 < 16; ++d4) {
                    float4 va = e0[d4], vb = e1[d4];
                    const float z0 = zr[4 * d4 + 0], z1 = zr[4 * d4 + 1];
                    const float z2 = zr[4 * d4 + 2], z3 = zr[4 * d4 + 3];
                    a0 = fmaf(va.x, z0, a0); a0 = fmaf(va.y, z1, a0);
                    a0 = fmaf(va.z, z2, a0); a0 = fmaf(va.w, z3, a0);
                    a1 = fmaf(vb.x, z0, a1); a1 = fmaf(vb.y, z1, a1);
                    a1 = fmaf(vb.z, z2, a1); a1 = fmaf(vb.w, z3, a1);
                }
            }
            {
                const float4* e2 = reinterpret_cast<const float4*>(lds_e + (kk + 2) * Dd);
                const float4* e3 = reinterpret_cast<const float4*>(lds_e + (kk + 3) * Dd);
#pragma unroll
                for (int d4 = 0; d4 < 16; ++d4) {
                    float4 vc = e2[d4], vd = e3[d4];
                    const float z0 = zr[4 * d4 + 0], z1 = zr[4 * d4 + 1];
                    const float z2 = zr[4 * d4 + 2], z3 = zr[4 * d4 + 3];
                    a2 = fmaf(vc.x, z0, a2); a2 = fmaf(vc.y, z1, a2);
                    a2 = fmaf(vc.z, z2, a2); a2 = fmaf(vc.w, z3, a2);
                    a3 = fmaf(vd.x, z0, a3); a3 = fmaf(vd.y, z1, a3);
                    a3 = fmaf(vd.z, z2, a3); a3 = fmaf(vd.w, z3, a3);
                }
            }
            // Reference-order fp32: t1 = round(zsq + esq), s = round(t1 - 2*dot)
            const float t10 = zsq + lds_p[kk + 0];
            const float t11 = zsq + lds_p[kk + 1];
            const float t12 = zsq + lds_p[kk + 2];
            const float t13 = zsq + lds_p[kk + 3];
            const float s0 = fmaf(-2.f, a0, t10);
            const float s1 = fmaf(-2.f, a1, t11);
            const float s2 = fmaf(-2.f, a2, t12);
            const float s3 = fmaf(-2.f, a3, t13);
            const int kg = c + kk;
            if (s0 < best) { best = s0; bidx = kg + 0; }
            if (s1 < best) { best = s1; bidx = kg + 1; }
            if (s2 < best) { best = s2; bidx = kg + 2; }
            if (s3 < best) { best = s3; bidx = kg + 3; }
        }
    }

    s_best[sp][rl] = best;
    s_bidx[sp][rl] = bidx;
    __syncthreads();
    if (sp == 0) {
#pragma unroll
        for (int s = 1; s < SPLITS; ++s) {
            const float ob = s_best[s][rl];
            const int oi = s_bidx[s][rl];
            if (ob < best || (ob == best && oi < bidx)) { best = ob; bidx = oi; }
        }
        codes_i[row] = bidx;
        out[row] = (float)bidx;
    }
}

// ---------------- Kernel B: quantized + loss partials ----------------
__global__ void __launch_bounds__(256) quant_kernel(
    const float* __restrict__ z, const float* __restrict__ cb,
    const int* __restrict__ codes_i, float* __restrict__ out,
    float* __restrict__ partials)
{
    const int row = blockIdx.x * 256 + threadIdx.x;  // grid = 256 blocks
    const int b = row >> 13;
    const int t = row & (Tt - 1);
    const int code = codes_i[row];
    const float4* crow = reinterpret_cast<const float4*>(cb + (size_t)code * Dd);
    const float* zbase = z + (size_t)b * (Dd * Tt) + t;
    float* obase = out + OUT_Q_OFF + (size_t)b * (Dd * Tt) + t;

    float acc = 0.f;
#pragma unroll
    for (int d4 = 0; d4 < 16; ++d4) {
        float4 v = crow[d4];
        float vv[4] = {v.x, v.y, v.z, v.w};
#pragma unroll
        for (int j = 0; j < 4; ++j) {
            const int d = d4 * 4 + j;
            const float zv = zbase[(size_t)d * Tt];
            const float diff = vv[j] - zv;
            acc = fmaf(diff, diff, acc);
            obase[(size_t)d * Tt] = vv[j];
        }
    }

    __shared__ float red[256];
    red[threadIdx.x] = acc;
    __syncthreads();
#pragma unroll
    for (int s = 128; s > 0; s >>= 1) {
        if (threadIdx.x < s) red[threadIdx.x] += red[threadIdx.x + s];
        __syncthreads();
    }
    if (threadIdx.x == 0) partials[blockIdx.x] = red[0];
}

// ---------------- Kernel C: final loss reduce ----------------
__global__ void __launch_bounds__(256) loss_kernel(const float* __restrict__ partials,
                                                   float* __restrict__ out) {
    __shared__ float red[256];
    red[threadIdx.x] = partials[threadIdx.x];  // exactly 256 partials
    __syncthreads();
#pragma unroll
    for (int s = 128; s > 0; s >>= 1) {
        if (threadIdx.x < s) red[threadIdx.x] += red[threadIdx.x + s];
        __syncthreads();
    }
    if (threadIdx.x == 0)
        out[OUT_LOSS_OFF] = red[0] * (1.0f / (float)NTOT);
}

extern "C" void kernel_launch(void* const* d_in, const int* in_sizes, int n_in,
                              void* d_out, int out_size, void* d_ws, size_t ws_size,
                              hipStream_t stream) {
    const float* z = (const float*)d_in[0];
    const float* cb = (const float*)d_in[1];
    float* out = (float*)d_out;

    char* ws = (char*)d_ws;
    int* codes_i = (int*)(ws + WS_CODES_OFF);
    float* prec = (float*)(ws + WS_PREC_OFF);
    float* partials = (float*)(ws + WS_PART_OFF);

    prec_kernel<<<(Kk + 255) / 256, 256, 0, stream>>>(cb, prec);
    argmin_kernel<<<BT / ROWS_PB, 256, 0, stream>>>(z, cb, prec, out, codes_i);
    quant_kernel<<<BT / 256, 256, 0, stream>>>(z, cb, codes_i, out, partials);
    loss_kernel<<<1, 256, 0, stream>>>(partials, out);
}